// Round 6
// baseline (174.354 us; speedup 1.0000x reference)
//
#include <hip/hip_runtime.h>
#include <math.h>

#define NSPK 2048
#define GUT  10
#define DIM  512
#define NG   (NSPK*GUT)

#define BM 128
#define BN 128
#define BK 64
#define NCB (NSPK/BN)   // 16 column blocks
#define NHB (NCB*2)     // 32 column half-blocks (64 cols each) -- one per wave
#define NRB (NG/BM)     // 160 row blocks
#define NKC (DIM/BK)    // 8 K-iterations

typedef __attribute__((ext_vector_type(4))) int   int4v;
typedef __attribute__((ext_vector_type(4))) float f32x4;

#define QMAX 32512.0f   // 127*256 + 127 -> h,l both fit int8

__device__ inline void gload_lds16(const void* g, void* l) {
  __builtin_amdgcn_global_load_lds(
      (const __attribute__((address_space(1))) void*)g,
      (__attribute__((address_space(3))) void*)l, 16, 0, 0);
}

__device__ inline void split16(float v, float qs, int& h, int& l) {
  const int q = (int)rintf(v * qs);            // |q| <= 32512
  h = (q + 128) >> 8;                          // round(q/256), in [-127,127]
  l = q - (h << 8);                            // in [-128,127]
}

// ---------------- Kernel 1: per-speaker prep (+ i8 h/l emit + scales) ----------------
__global__ __launch_bounds__(256) void k1_prep(const float* __restrict__ x,
    unsigned short* __restrict__ xn_h, unsigned short* __restrict__ xn_l,
    unsigned short* __restrict__ cn_h, unsigned short* __restrict__ cn_l,
    float* __restrict__ xs, float* __restrict__ cs, float* __restrict__ diag)
{
  const int n = blockIdx.x;
  const int t = threadIdx.x;
  const float* xb = x + (size_t)n * GUT * DIM + 2 * t;

  float2 xv[GUT];
#pragma unroll
  for (int g = 0; g < GUT; ++g)
    xv[g] = *reinterpret_cast<const float2*>(xb + g * DIM);

  float sx = 0.f, sy = 0.f;
#pragma unroll
  for (int g = 0; g < GUT; ++g) { sx += xv[g].x; sy += xv[g].y; }

  float part[21], pm[11];
#pragma unroll
  for (int g = 0; g < GUT; ++g) {
    part[g]      = xv[g].x * xv[g].x + xv[g].y * xv[g].y;
    part[10 + g] = xv[g].x * sx + xv[g].y * sy;
    pm[g]        = fmaxf(fabsf(xv[g].x), fabsf(xv[g].y));
  }
  part[20] = sx * sx + sy * sy;
  pm[10]   = fmaxf(fabsf(sx), fabsf(sy));

  __shared__ float wred[21][4], wred2[11][4];
  __shared__ float res[21], res2[11];
  const int lane = t & 63, wid = t >> 6;
#pragma unroll
  for (int q = 0; q < 21; ++q) {
    float v = part[q];
    for (int off = 32; off > 0; off >>= 1) v += __shfl_down(v, off);
    if (lane == 0) wred[q][wid] = v;
  }
#pragma unroll
  for (int q = 0; q < 11; ++q) {
    float v = pm[q];
    for (int off = 32; off > 0; off >>= 1) v = fmaxf(v, __shfl_down(v, off));
    if (lane == 0) wred2[q][wid] = v;
  }
  __syncthreads();
  if (t < 21) res[t] = wred[t][0] + wred[t][1] + wred[t][2] + wred[t][3];
  if (t < 11) res2[t] = fmaxf(fmaxf(wred2[t][0], wred2[t][1]), fmaxf(wred2[t][2], wred2[t][3]));
  __syncthreads();

  const float psum = res[20];
  {
    const float csummax = res2[10];
    const float cnorm = sqrtf(psum) * (1.0f / GUT);
    const float cscale = (1.0f / GUT) / fmaxf(cnorm, 1e-8f);   // c_i = sum_i * cscale
    const float qs = QMAX / csummax;
    int h0, l0, h1, l1;
    split16(sx, qs, h0, l0);
    split16(sy, qs, h1, l1);
    cn_h[n * (DIM / 2) + t] = (unsigned short)(((unsigned)(unsigned char)h1 << 8) | (unsigned char)h0);
    cn_l[n * (DIM / 2) + t] = (unsigned short)(((unsigned)(unsigned char)l1 << 8) | (unsigned char)l0);
    if (t == 0) cs[n] = cscale * csummax * (1.0f / QMAX);
  }

#pragma unroll
  for (int g = 0; g < GUT; ++g) {
    const float rowmax = res2[g];
    const float sc = 1.0f / fmaxf(sqrtf(res[g]), 1e-8f);       // xn_i = x_i * sc
    const float qs = QMAX / rowmax;
    int h0, l0, h1, l1;
    split16(xv[g].x, qs, h0, l0);
    split16(xv[g].y, qs, h1, l1);
    const size_t row = (size_t)n * GUT + g;
    xn_h[row * (DIM / 2) + t] = (unsigned short)(((unsigned)(unsigned char)h1 << 8) | (unsigned char)h0);
    xn_l[row * (DIM / 2) + t] = (unsigned short)(((unsigned)(unsigned char)l1 << 8) | (unsigned char)l0);
    if (t == 0) xs[row] = sc * rowmax * (1.0f / QMAX);
  }

  if (t < GUT) {
    const int g = t;
    const float psq = res[g], pd = res[10 + g];
    const float dxe = (pd - psq) * (1.0f / (GUT - 1));
    float ne2 = (psum - 2.f * pd + psq) * (1.0f / ((GUT - 1) * (GUT - 1)));
    ne2 = fmaxf(ne2, 0.f);
    const float dnm = fmaxf(sqrtf(psq), 1e-8f) * fmaxf(sqrtf(ne2), 1e-8f);
    diag[n * GUT + g] = dxe / dnm;
  }
}

// ---------------- Kernel 2: i8 split MFMA GEMM, 2-deep pipelined, fixed-max softmax ----------------
// sim = xs[row]*cs[col]*256*(256*hh + (hl+lh)); l*l term dropped (~2.5e-6 err).
// BK=64, LDS double-buffered (2x32KB). Per iter: STAGE(next) -> vmcnt(8) -> barrier
// -> ds_read+MFMA -> lgkmcnt(0)+barrier. Counted vmcnt keeps prefetch in flight.
// Swizzle: phys chunk = logical ^ ((row>>1)&3) -- spreads b128 reads 2-way over
// all 8 chunk-columns (64B rows = 2 rows per 128B bank line).
__global__ __launch_bounds__(256, 2) void k2_mfma(
    const unsigned char* __restrict__ xn_h, const unsigned char* __restrict__ xn_l,
    const unsigned char* __restrict__ cn_h, const unsigned char* __restrict__ cn_l,
    const float* __restrict__ xs, const float* __restrict__ cs,
    const float* __restrict__ diag, const float* __restrict__ wp,
    const float* __restrict__ bp, float* __restrict__ partial)
{
  __shared__ char ldsb[2 * 32768];            // 64 KB: 2 bufs x {AH,AL,BH,BL}[128][64]

  const int tid = threadIdx.x;
  const int l = tid & 63, w = tid >> 6;
  const int rb = blockIdx.x >> 4, cb = blockIdx.x & 15;
  const int rowbase = rb * BM, colbase = cb * BN;

  int4v acc1[4][4], acc2[4][4];
#pragma unroll
  for (int i = 0; i < 4; ++i)
#pragma unroll
    for (int j = 0; j < 4; ++j)
#pragma unroll
      for (int e = 0; e < 4; ++e) { acc1[i][j][e] = 0; acc2[i][j][e] = 0; }

  // Staging: each 1024B instr covers 16 rows (64B/row); lane l -> row i*16+(l>>2),
  // phys chunk (l&3). Source logical chunk = (l&3)^((row>>1)&3) = (l&3)^((l>>3)&3).
  const int sR = l >> 2;
  const int sC16 = (((l & 3) ^ ((l >> 3) & 3)) << 4);

  // Fragment reads: row = 16f+lr, logical k-chunk lq; phys chunk = lq^((lr>>1)&3).
  const int wr = w >> 1, wc = w & 1;
  const int lr = l & 15, lq = l >> 4;
  int aRel[4], bRel[4];
#pragma unroll
  for (int f = 0; f < 4; ++f) {
    aRel[f] = ((wr * 64 + f * 16 + lr) << 6) + ((lq ^ ((lr >> 1) & 3)) << 4);
    bRel[f] = ((wc * 64 + f * 16 + lr) << 6) + ((lq ^ ((lr >> 1) & 3)) << 4);
  }

#define STAGE(buf, kcn) do {                                                   \
    char* dst_ = ldsb + (buf) * 32768;                                         \
    _Pragma("unroll")                                                          \
    for (int q_ = 0; q_ < 2; ++q_) {                                           \
      const int i_ = w * 2 + q_;                                               \
      const size_t ao_ = (size_t)(rowbase + i_ * 16 + sR) * DIM + (kcn) * BK + sC16; \
      const size_t bo_ = (size_t)(colbase + i_ * 16 + sR) * DIM + (kcn) * BK + sC16; \
      gload_lds16(xn_h + ao_, dst_ +     0 + i_ * 1024);                       \
      gload_lds16(xn_l + ao_, dst_ +  8192 + i_ * 1024);                       \
      gload_lds16(cn_h + bo_, dst_ + 16384 + i_ * 1024);                       \
      gload_lds16(cn_l + bo_, dst_ + 24576 + i_ * 1024);                       \
    }                                                                          \
  } while (0)

  STAGE(0, 0);

  for (int kc = 0; kc < NKC; ++kc) {
    const int cur = kc & 1;
    if (kc < NKC - 1) {
      STAGE(cur ^ 1, kc + 1);
      asm volatile("s_waitcnt vmcnt(8)" ::: "memory");   // cur's 8 loads done; next 8 in flight
    } else {
      asm volatile("s_waitcnt vmcnt(0)" ::: "memory");
    }
    __builtin_amdgcn_s_barrier();

    const char* base = ldsb + cur * 32768;
    int4v ah[4], al4[4], bh4[4], bl4[4];
#pragma unroll
    for (int f = 0; f < 4; ++f) {            // h-fragments first: hh MFMAs can start early
      ah[f]  = *reinterpret_cast<const int4v*>(base +     0 + aRel[f]);
      bh4[f] = *reinterpret_cast<const int4v*>(base + 16384 + bRel[f]);
    }
#pragma unroll
    for (int f = 0; f < 4; ++f) {
      al4[f] = *reinterpret_cast<const int4v*>(base +  8192 + aRel[f]);
      bl4[f] = *reinterpret_cast<const int4v*>(base + 24576 + bRel[f]);
    }
    __builtin_amdgcn_s_setprio(1);
#pragma unroll
    for (int mf = 0; mf < 4; ++mf)
#pragma unroll
      for (int nf = 0; nf < 4; ++nf) {
        acc1[mf][nf] = __builtin_amdgcn_mfma_i32_16x16x64_i8(ah[mf], bh4[nf], acc1[mf][nf], 0, 0, 0);
        acc2[mf][nf] = __builtin_amdgcn_mfma_i32_16x16x64_i8(ah[mf], bl4[nf], acc2[mf][nf], 0, 0, 0);
        acc2[mf][nf] = __builtin_amdgcn_mfma_i32_16x16x64_i8(al4[mf], bh4[nf], acc2[mf][nf], 0, 0, 0);
      }
    __builtin_amdgcn_s_setprio(0);

    if (kc < NKC - 1) {
      asm volatile("s_waitcnt lgkmcnt(0)" ::: "memory"); // reads complete before buf reuse
      __builtin_amdgcn_s_barrier();
    }
  }
#undef STAGE

  // ---- epilogue: fixed-max softmax. C/D layout col=lane&15, row=(lane>>4)*4+reg ----
  const float wv = wp[0], bvb = bp[0];
  const float MFIX = fabsf(wv) + bvb;                    // upper bound on logits
  float xc4[4];
#pragma unroll
  for (int nf = 0; nf < 4; ++nf)
    xc4[nf] = cs[colbase + wc * 64 + nf * 16 + lr] * 256.0f;

#pragma unroll
  for (int mf = 0; mf < 4; ++mf) {
#pragma unroll
    for (int r = 0; r < 4; ++r) {
      const int row = rowbase + wr * 64 + mf * 16 + lq * 4 + r;
      const int n = row / GUT;
      const int tcol = n - colbase;
      const float dval = (tcol >= 0 && tcol < BN) ? diag[row] : 0.f;
      const float xsr = xs[row];
      float se = 0.f, bvv = -__builtin_inff(), tg = -__builtin_inff();
      int bi = 0x7fffffff;
#pragma unroll
      for (int nf = 0; nf < 4; ++nf) {
        const int coll = wc * 64 + nf * 16 + lr;
        float s = (xsr * xc4[nf]) *
                  fmaf(256.0f, (float)acc1[mf][nf][r], (float)acc2[mf][nf][r]);
        if (coll == tcol) s = dval;
        s = fmaxf(s, 1e-6f);
        const float L = fmaf(s, wv, bvb);
        se += __expf(L - MFIX);
        tg = (coll == tcol) ? L : tg;
        if (L > bvv) { bvv = L; bi = colbase + coll; }
      }
#pragma unroll
      for (int off = 1; off < 16; off <<= 1) {
        se += __shfl_xor(se, off);
        const float obv = __shfl_xor(bvv, off);
        const int   obi = __shfl_xor(bi, off);
        tg = fmaxf(tg, __shfl_xor(tg, off));
        if (obv > bvv || (obv == bvv && obi < bi)) { bvv = obv; bi = obi; }
      }
      if (lr == 0) {
        f32x4 slot;
        slot[0] = se; slot[1] = bvv; slot[2] = __int_as_float(bi); slot[3] = tg;
        *reinterpret_cast<f32x4*>(partial + ((size_t)row * NHB + cb * 2 + wc) * 4) = slot;
      }
    }
  }
}

// ---------------- Kernel 3: merge 32 half-block partials per row (pure sums) ----------------
__global__ __launch_bounds__(256) void k3_rows(const float* __restrict__ partial,
    const float* __restrict__ wp, const float* __restrict__ bp,
    float* __restrict__ rlp, float* __restrict__ rcr)
{
  const int row = blockIdx.x * 256 + threadIdx.x;
  const float MFIX = fabsf(wp[0]) + bp[0];
  const f32x4* p = reinterpret_cast<const f32x4*>(partial + (size_t)row * NHB * 4);
  float se = 0.f, bv = -__builtin_inff(), tg = -__builtin_inff();
  int bi = 0x7fffffff;
#pragma unroll
  for (int c = 0; c < NHB; ++c) {
    const f32x4 v = p[c];
    se += v[0];
    const int i2 = __float_as_int(v[2]);
    if (v[1] > bv || (v[1] == bv && i2 < bi)) { bv = v[1]; bi = i2; }
    tg = fmaxf(tg, v[3]);
  }
  rlp[row] = tg - MFIX - logf(se);
  rcr[row] = (bi == row / GUT) ? 1.0f : 0.0f;
}

// ---------------- Kernel 4: final scalar reduction ----------------
__global__ __launch_bounds__(256) void k4_reduce(const float* __restrict__ row_logp,
    const float* __restrict__ row_corr, float* __restrict__ out)
{
  const int t = threadIdx.x;
  float sl = 0.f, sc = 0.f;
  for (int i = t; i < NG; i += 256) { sl += row_logp[i]; sc += row_corr[i]; }
  for (int off = 32; off > 0; off >>= 1) { sl += __shfl_down(sl, off); sc += __shfl_down(sc, off); }
  __shared__ float ra[4], rb2[4];
  const int lane = t & 63, wid = t >> 6;
  if (lane == 0) { ra[wid] = sl; rb2[wid] = sc; }
  __syncthreads();
  if (t == 0) {
    const float S = ra[0] + ra[1] + ra[2] + ra[3];
    const float C = rb2[0] + rb2[1] + rb2[2] + rb2[3];
    out[0] = -(S * (1.0f / NG));
    out[1] = C * (100.0f / NG);
  }
}

extern "C" void kernel_launch(void* const* d_in, const int* in_sizes, int n_in,
                              void* d_out, int out_size, void* d_ws, size_t ws_size,
                              hipStream_t stream)
{
  const float* x = (const float*)d_in[0];
  const float* w = (const float*)d_in[1];
  const float* b = (const float*)d_in[2];
  float* out = (float*)d_out;

  char* ws = (char*)d_ws;
  unsigned short* xn_h = (unsigned short*)ws;                         // NG*512 i8
  unsigned short* xn_l = (unsigned short*)(ws + (size_t)NG * DIM);    // NG*512 i8
  unsigned short* cn_h = (unsigned short*)(ws + (size_t)NG * DIM * 2);
  unsigned short* cn_l = (unsigned short*)(ws + (size_t)NG * DIM * 2 + (size_t)NSPK * DIM);
  char* after = ws + (size_t)NG * DIM * 2 + (size_t)NSPK * DIM * 2;
  float* xs   = (float*)after;                                        // NG
  float* cs   = xs + NG;                                              // NSPK
  float* diag = cs + NSPK;                                            // NG
  float* part = diag + NG;                                            // NG*32*4
  float* rlp  = part + (size_t)NG * NHB * 4;                          // NG
  float* rcr  = rlp + NG;                                             // NG

  hipLaunchKernelGGL(k1_prep, dim3(NSPK), dim3(256), 0, stream,
                     x, xn_h, xn_l, cn_h, cn_l, xs, cs, diag);
  hipLaunchKernelGGL(k2_mfma, dim3(NRB * NCB), dim3(256), 0, stream,
                     (const unsigned char*)xn_h, (const unsigned char*)xn_l,
                     (const unsigned char*)cn_h, (const unsigned char*)cn_l,
                     xs, cs, diag, w, b, part);
  hipLaunchKernelGGL(k3_rows, dim3(NG / 256), dim3(256), 0, stream, part, w, b, rlp, rcr);
  hipLaunchKernelGGL(k4_reduce, dim3(1), dim3(256), 0, stream, rlp, rcr, out);
}

// Round 8
// 124.718 us; speedup vs baseline: 1.3980x; 1.3980x over previous
//
#include <hip/hip_runtime.h>
#include <math.h>

#define NSPK 2048
#define GUT  10
#define DIM  512
#define NG   (NSPK*GUT)

#define BM 128
#define BN 128
#define BK 64
#define NCB (NSPK/BN)   // 16 column blocks
#define NHB (NCB*2)     // 32 column half-blocks (64 cols each) -- one per wave
#define NRB (NG/BM)     // 160 row blocks
#define NKC (DIM/BK)    // 8 K-iterations

typedef __attribute__((ext_vector_type(4))) int   int4v;
typedef __attribute__((ext_vector_type(4))) float f32x4;

__device__ inline void gload_lds16(const void* g, void* l) {
  __builtin_amdgcn_global_load_lds(
      (const __attribute__((address_space(1))) void*)g,
      (__attribute__((address_space(3))) void*)l, 16, 0, 0);
}

// ---------------- Kernel 1: per-speaker prep (+ single-i8 emit + scales) ----------------
// Single int8 quantization: q = rint(v * 127/rowmax); sim error sigma ~6.5e-4,
// target logit exact (fp32 diag) -> loss/prec err ~1e-4, far under threshold.
__global__ __launch_bounds__(256) void k1_prep(const float* __restrict__ x,
    unsigned short* __restrict__ xn8, unsigned short* __restrict__ cn8,
    float* __restrict__ xs, float* __restrict__ cs, float* __restrict__ diag)
{
  const int n = blockIdx.x;
  const int t = threadIdx.x;
  const float* xb = x + (size_t)n * GUT * DIM + 2 * t;

  float2 xv[GUT];
#pragma unroll
  for (int g = 0; g < GUT; ++g)
    xv[g] = *reinterpret_cast<const float2*>(xb + g * DIM);

  float sx = 0.f, sy = 0.f;
#pragma unroll
  for (int g = 0; g < GUT; ++g) { sx += xv[g].x; sy += xv[g].y; }

  float part[21], pm[11];
#pragma unroll
  for (int g = 0; g < GUT; ++g) {
    part[g]      = xv[g].x * xv[g].x + xv[g].y * xv[g].y;
    part[10 + g] = xv[g].x * sx + xv[g].y * sy;
    pm[g]        = fmaxf(fabsf(xv[g].x), fabsf(xv[g].y));
  }
  part[20] = sx * sx + sy * sy;
  pm[10]   = fmaxf(fabsf(sx), fabsf(sy));

  __shared__ float wred[21][4], wred2[11][4];
  __shared__ float res[21], res2[11];
  const int lane = t & 63, wid = t >> 6;
#pragma unroll
  for (int q = 0; q < 21; ++q) {
    float v = part[q];
    for (int off = 32; off > 0; off >>= 1) v += __shfl_down(v, off);
    if (lane == 0) wred[q][wid] = v;
  }
#pragma unroll
  for (int q = 0; q < 11; ++q) {
    float v = pm[q];
    for (int off = 32; off > 0; off >>= 1) v = fmaxf(v, __shfl_down(v, off));
    if (lane == 0) wred2[q][wid] = v;
  }
  __syncthreads();
  if (t < 21) res[t] = wred[t][0] + wred[t][1] + wred[t][2] + wred[t][3];
  if (t < 11) res2[t] = fmaxf(fmaxf(wred2[t][0], wred2[t][1]), fmaxf(wred2[t][2], wred2[t][3]));
  __syncthreads();

  const float psum = res[20];
  {
    const float csummax = res2[10];
    const float cnorm = sqrtf(psum) * (1.0f / GUT);
    const float cscale = (1.0f / GUT) / fmaxf(cnorm, 1e-8f);   // c_i = sum_i * cscale
    const float qs = 127.0f / csummax;
    const int q0 = (int)rintf(sx * qs), q1 = (int)rintf(sy * qs);
    cn8[n * (DIM / 2) + t] = (unsigned short)(((unsigned)(unsigned char)q1 << 8) | (unsigned char)q0);
    if (t == 0) cs[n] = cscale * csummax * (1.0f / 127.0f);
  }

#pragma unroll
  for (int g = 0; g < GUT; ++g) {
    const float rowmax = res2[g];
    const float sc = 1.0f / fmaxf(sqrtf(res[g]), 1e-8f);       // xn_i = x_i * sc
    const float qs = 127.0f / rowmax;
    const int q0 = (int)rintf(xv[g].x * qs), q1 = (int)rintf(xv[g].y * qs);
    const size_t row = (size_t)n * GUT + g;
    xn8[row * (DIM / 2) + t] = (unsigned short)(((unsigned)(unsigned char)q1 << 8) | (unsigned char)q0);
    if (t == 0) xs[row] = sc * rowmax * (1.0f / 127.0f);
  }

  if (t < GUT) {
    const int g = t;
    const float psq = res[g], pd = res[10 + g];
    const float dxe = (pd - psq) * (1.0f / (GUT - 1));
    float ne2 = (psum - 2.f * pd + psq) * (1.0f / ((GUT - 1) * (GUT - 1)));
    ne2 = fmaxf(ne2, 0.f);
    const float dnm = fmaxf(sqrtf(psq), 1e-8f) * fmaxf(sqrtf(ne2), 1e-8f);
    diag[n * GUT + g] = dxe / dnm;
  }
}

// ---------------- Kernel 2: single-i8 MFMA GEMM, 2-deep pipelined, fixed-max softmax ----------------
// sim = xs[row]*cs[col]*(i32 dot). BK=64, LDS dbuf 2x{A[128][64],B[128][64]} = 32KB.
// Per iter: STAGE(next)[4 vmem/wave] -> vmcnt(4) -> barrier -> ds_read+MFMA ->
// lgkmcnt(0)+barrier. Counted vmcnt keeps prefetch in flight (round-6-proven shape).
// Swizzle: phys chunk = logical ^ ((row>>1)&3) (2-way = free; conflict-free measured).
__global__ __launch_bounds__(256, 3) void k2_mfma(
    const unsigned char* __restrict__ xn8, const unsigned char* __restrict__ cn8,
    const float* __restrict__ xs, const float* __restrict__ cs,
    const float* __restrict__ diag, const float* __restrict__ wp,
    const float* __restrict__ bp, float* __restrict__ partial)
{
  __shared__ char ldsb[2 * 16384];            // 32 KB: 2 bufs x {A[8KB], B[8KB]}

  const int tid = threadIdx.x;
  const int l = tid & 63, w = tid >> 6;
  const int rb = blockIdx.x >> 4, cb = blockIdx.x & 15;
  const int rowbase = rb * BM, colbase = cb * BN;

  int4v acc1[4][4];
#pragma unroll
  for (int i = 0; i < 4; ++i)
#pragma unroll
    for (int j = 0; j < 4; ++j)
#pragma unroll
      for (int e = 0; e < 4; ++e) acc1[i][j][e] = 0;

  // Staging: 1024B instr = 16 rows x 64B; lane l -> row i*16+(l>>2), phys chunk l&3.
  // Source logical chunk = (l&3)^((row>>1)&3) = (l&3)^((l>>3)&3)  [rule-21 involution].
  const int sR = l >> 2;
  const int sC16 = (((l & 3) ^ ((l >> 3) & 3)) << 4);

  // Frag reads: row = 16f+lr (+wave offset), logical chunk lq; phys = lq^((lr>>1)&3).
  const int wr = w >> 1, wc = w & 1;
  const int lr = l & 15, lq = l >> 4;
  int aRel[4], bRel[4];
#pragma unroll
  for (int f = 0; f < 4; ++f) {
    aRel[f] = ((wr * 64 + f * 16 + lr) << 6) + ((lq ^ ((lr >> 1) & 3)) << 4);
    bRel[f] = ((wc * 64 + f * 16 + lr) << 6) + ((lq ^ ((lr >> 1) & 3)) << 4);
  }

#define STAGE(buf, kcn) do {                                                   \
    char* dst_ = ldsb + (buf) * 16384;                                         \
    _Pragma("unroll")                                                          \
    for (int q_ = 0; q_ < 2; ++q_) {                                           \
      const int i_ = w * 2 + q_;                                               \
      const size_t ao_ = (size_t)(rowbase + i_ * 16 + sR) * DIM + (size_t)(kcn) * BK + sC16; \
      const size_t bo_ = (size_t)(colbase + i_ * 16 + sR) * DIM + (size_t)(kcn) * BK + sC16; \
      gload_lds16(xn8 + ao_, dst_ + i_ * 1024);                                \
      gload_lds16(cn8 + bo_, dst_ + 8192 + i_ * 1024);                         \
    }                                                                          \
  } while (0)

  STAGE(0, 0);

  for (int kc = 0; kc < NKC; ++kc) {
    const int cur = kc & 1;
    if (kc < NKC - 1) {
      STAGE(cur ^ 1, kc + 1);
      asm volatile("s_waitcnt vmcnt(4)" ::: "memory");   // cur's 4 loads done; next 4 in flight
    } else {
      asm volatile("s_waitcnt vmcnt(0)" ::: "memory");
    }
    __builtin_amdgcn_s_barrier();

    const char* base = ldsb + cur * 16384;
    int4v ah[4], bh4[4];
#pragma unroll
    for (int f = 0; f < 4; ++f) {
      ah[f]  = *reinterpret_cast<const int4v*>(base + aRel[f]);
      bh4[f] = *reinterpret_cast<const int4v*>(base + 8192 + bRel[f]);
    }
    __builtin_amdgcn_s_setprio(1);
#pragma unroll
    for (int mf = 0; mf < 4; ++mf)
#pragma unroll
      for (int nf = 0; nf < 4; ++nf)
        acc1[mf][nf] = __builtin_amdgcn_mfma_i32_16x16x64_i8(ah[mf], bh4[nf], acc1[mf][nf], 0, 0, 0);
    __builtin_amdgcn_s_setprio(0);

    if (kc < NKC - 1) {
      asm volatile("s_waitcnt lgkmcnt(0)" ::: "memory"); // reads complete before buf reuse
      __builtin_amdgcn_s_barrier();
    }
  }
#undef STAGE

  // ---- epilogue: fixed-max softmax. C/D layout col=lane&15, row=(lane>>4)*4+reg ----
  const float wv = wp[0], bvb = bp[0];
  const float MFIX = fabsf(wv) + bvb;                    // upper bound on logits
  float xc4[4];
#pragma unroll
  for (int nf = 0; nf < 4; ++nf)
    xc4[nf] = cs[colbase + wc * 64 + nf * 16 + lr];

#pragma unroll
  for (int mf = 0; mf < 4; ++mf) {
#pragma unroll
    for (int r = 0; r < 4; ++r) {
      const int row = rowbase + wr * 64 + mf * 16 + lq * 4 + r;
      const int n = row / GUT;
      const int tcol = n - colbase;
      const float dval = (tcol >= 0 && tcol < BN) ? diag[row] : 0.f;
      const float xsr = xs[row];
      float se = 0.f, bvv = -__builtin_inff(), tg = -__builtin_inff();
      int bi = 0x7fffffff;
#pragma unroll
      for (int nf = 0; nf < 4; ++nf) {
        const int coll = wc * 64 + nf * 16 + lr;
        float s = (xsr * xc4[nf]) * (float)acc1[mf][nf][r];
        if (coll == tcol) s = dval;
        s = fmaxf(s, 1e-6f);
        const float L = fmaf(s, wv, bvb);
        se += __expf(L - MFIX);
        tg = (coll == tcol) ? L : tg;
        if (L > bvv) { bvv = L; bi = colbase + coll; }
      }
#pragma unroll
      for (int off = 1; off < 16; off <<= 1) {
        se += __shfl_xor(se, off);
        const float obv = __shfl_xor(bvv, off);
        const int   obi = __shfl_xor(bi, off);
        tg = fmaxf(tg, __shfl_xor(tg, off));
        if (obv > bvv || (obv == bvv && obi < bi)) { bvv = obv; bi = obi; }
      }
      if (lr == 0) {
        f32x4 slot;
        slot[0] = se; slot[1] = bvv; slot[2] = __int_as_float(bi); slot[3] = tg;
        *reinterpret_cast<f32x4*>(partial + ((size_t)row * NHB + cb * 2 + wc) * 4) = slot;
      }
    }
  }
}

// ---------------- Kernel 3: merge 32 half-block partials per row (pure sums) ----------------
__global__ __launch_bounds__(256) void k3_rows(const float* __restrict__ partial,
    const float* __restrict__ wp, const float* __restrict__ bp,
    float* __restrict__ rlp, float* __restrict__ rcr)
{
  const int row = blockIdx.x * 256 + threadIdx.x;
  const float MFIX = fabsf(wp[0]) + bp[0];
  const f32x4* p = reinterpret_cast<const f32x4*>(partial + (size_t)row * NHB * 4);
  float se = 0.f, bv = -__builtin_inff(), tg = -__builtin_inff();
  int bi = 0x7fffffff;
#pragma unroll
  for (int c = 0; c < NHB; ++c) {
    const f32x4 v = p[c];
    se += v[0];
    const int i2 = __float_as_int(v[2]);
    if (v[1] > bv || (v[1] == bv && i2 < bi)) { bv = v[1]; bi = i2; }
    tg = fmaxf(tg, v[3]);
  }
  rlp[row] = tg - MFIX - logf(se);
  rcr[row] = (bi == row / GUT) ? 1.0f : 0.0f;
}

// ---------------- Kernel 4: final scalar reduction ----------------
__global__ __launch_bounds__(256) void k4_reduce(const float* __restrict__ row_logp,
    const float* __restrict__ row_corr, float* __restrict__ out)
{
  const int t = threadIdx.x;
  float sl = 0.f, sc = 0.f;
  for (int i = t; i < NG; i += 256) { sl += row_logp[i]; sc += row_corr[i]; }
  for (int off = 32; off > 0; off >>= 1) { sl += __shfl_down(sl, off); sc += __shfl_down(sc, off); }
  __shared__ float ra[4], rb2[4];
  const int lane = t & 63, wid = t >> 6;
  if (lane == 0) { ra[wid] = sl; rb2[wid] = sc; }
  __syncthreads();
  if (t == 0) {
    const float S = ra[0] + ra[1] + ra[2] + ra[3];
    const float C = rb2[0] + rb2[1] + rb2[2] + rb2[3];
    out[0] = -(S * (1.0f / NG));
    out[1] = C * (100.0f / NG);
  }
}

extern "C" void kernel_launch(void* const* d_in, const int* in_sizes, int n_in,
                              void* d_out, int out_size, void* d_ws, size_t ws_size,
                              hipStream_t stream)
{
  const float* x = (const float*)d_in[0];
  const float* w = (const float*)d_in[1];
  const float* b = (const float*)d_in[2];
  float* out = (float*)d_out;

  char* ws = (char*)d_ws;
  unsigned short* xn8 = (unsigned short*)ws;                          // NG*512 i8
  unsigned short* cn8 = (unsigned short*)(ws + (size_t)NG * DIM);     // NSPK*512 i8
  char* after = ws + (size_t)NG * DIM + (size_t)NSPK * DIM;
  float* xs   = (float*)after;                                        // NG
  float* cs   = xs + NG;                                              // NSPK
  float* diag = cs + NSPK;                                            // NG
  float* part = diag + NG;                                            // NG*32*4
  float* rlp  = part + (size_t)NG * NHB * 4;                          // NG
  float* rcr  = rlp + NG;                                             // NG

  hipLaunchKernelGGL(k1_prep, dim3(NSPK), dim3(256), 0, stream,
                     x, xn8, cn8, xs, cs, diag);
  hipLaunchKernelGGL(k2_mfma, dim3(NRB * NCB), dim3(256), 0, stream,
                     (const unsigned char*)xn8, (const unsigned char*)cn8,
                     xs, cs, diag, w, b, part);
  hipLaunchKernelGGL(k3_rows, dim3(NG / 256), dim3(256), 0, stream, part, w, b, rlp, rcr);
  hipLaunchKernelGGL(k4_reduce, dim3(1), dim3(256), 0, stream, rlp, rcr, out);
}

// Round 9
// 87.403 us; speedup vs baseline: 1.9948x; 1.4269x over previous
//
#include <hip/hip_runtime.h>
#include <math.h>

#define NSPK 2048
#define GUT  10
#define DIM  512
#define NG   (NSPK*GUT)

#define BM 128
#define BN 128
#define BK 64
#define NCB (NSPK/BN)   // 16 column blocks
#define NHB (NCB*2)     // 32 column half-blocks (64 cols each)
#define NRB (NG/BM)     // 160 row blocks
#define NKC (DIM/BK)    // 8 K-iterations

typedef __attribute__((ext_vector_type(4))) int int4v;

__device__ inline void gload_lds16(const void* g, void* l) {
  __builtin_amdgcn_global_load_lds(
      (const __attribute__((address_space(1))) void*)g,
      (__attribute__((address_space(3))) void*)l, 16, 0, 0);
}

__device__ inline float wsumf(float v) {
#pragma unroll
  for (int m = 1; m < 64; m <<= 1) v += __shfl_xor(v, m);
  return v;
}
__device__ inline float wmaxf(float v) {
#pragma unroll
  for (int m = 1; m < 64; m <<= 1) v = fmaxf(v, __shfl_xor(v, m));
  return v;
}
__device__ inline unsigned pack4i8(float a, float b, float c, float d, float qs) {
  const int q0 = (int)rintf(a * qs) & 255, q1 = (int)rintf(b * qs) & 255;
  const int q2 = (int)rintf(c * qs) & 255, q3 = (int)rintf(d * qs) & 255;
  return (unsigned)q0 | ((unsigned)q1 << 8) | ((unsigned)q2 << 16) | ((unsigned)q3 << 24);
}

// ---------------- Kernel 1: one WAVE per speaker; no LDS, no __syncthreads ----------------
// lane l owns elems [8l, 8l+8). All reductions wave-local (xor-butterfly -> all lanes hold result).
__global__ __launch_bounds__(64) void k1_prep(const float* __restrict__ x,
    unsigned char* __restrict__ xn8, unsigned char* __restrict__ cn8,
    float* __restrict__ xs, float* __restrict__ cs, float* __restrict__ diag)
{
  const int n = blockIdx.x;
  const int l = threadIdx.x;
  const float* xb = x + (size_t)n * GUT * DIM + l * 8;

  float4 xa[GUT], xc[GUT];
#pragma unroll
  for (int g = 0; g < GUT; ++g) {
    xa[g] = *reinterpret_cast<const float4*>(xb + g * DIM);
    xc[g] = *reinterpret_cast<const float4*>(xb + g * DIM + 4);
  }
  float s0=0,s1=0,s2=0,s3=0,s4=0,s5=0,s6=0,s7=0;
#pragma unroll
  for (int g = 0; g < GUT; ++g) {
    s0 += xa[g].x; s1 += xa[g].y; s2 += xa[g].z; s3 += xa[g].w;
    s4 += xc[g].x; s5 += xc[g].y; s6 += xc[g].z; s7 += xc[g].w;
  }
  float psq[GUT], pd[GUT], mxg[GUT];
#pragma unroll
  for (int g = 0; g < GUT; ++g) {
    psq[g] = xa[g].x*xa[g].x + xa[g].y*xa[g].y + xa[g].z*xa[g].z + xa[g].w*xa[g].w
           + xc[g].x*xc[g].x + xc[g].y*xc[g].y + xc[g].z*xc[g].z + xc[g].w*xc[g].w;
    pd[g]  = xa[g].x*s0 + xa[g].y*s1 + xa[g].z*s2 + xa[g].w*s3
           + xc[g].x*s4 + xc[g].y*s5 + xc[g].z*s6 + xc[g].w*s7;
    mxg[g] = fmaxf(fmaxf(fmaxf(fabsf(xa[g].x), fabsf(xa[g].y)), fmaxf(fabsf(xa[g].z), fabsf(xa[g].w))),
                   fmaxf(fmaxf(fabsf(xc[g].x), fabsf(xc[g].y)), fmaxf(fabsf(xc[g].z), fabsf(xc[g].w))));
  }
  float ps = s0*s0+s1*s1+s2*s2+s3*s3+s4*s4+s5*s5+s6*s6+s7*s7;
  float ms = fmaxf(fmaxf(fmaxf(fabsf(s0),fabsf(s1)),fmaxf(fabsf(s2),fabsf(s3))),
                   fmaxf(fmaxf(fabsf(s4),fabsf(s5)),fmaxf(fabsf(s6),fabsf(s7))));
#pragma unroll
  for (int g = 0; g < GUT; ++g) { psq[g]=wsumf(psq[g]); pd[g]=wsumf(pd[g]); mxg[g]=wmaxf(mxg[g]); }
  ps = wsumf(ps); ms = wmaxf(ms);

  // centroid quant (per-element i8, scale cs[n])
  const float cnorm  = sqrtf(ps) * (1.0f / GUT);
  const float cscale = (1.0f / GUT) / fmaxf(cnorm, 1e-8f);
  const float qsc = 127.0f / ms;
  uint2 cp; cp.x = pack4i8(s0,s1,s2,s3,qsc); cp.y = pack4i8(s4,s5,s6,s7,qsc);
  reinterpret_cast<uint2*>(cn8)[n * 64 + l] = cp;

#pragma unroll
  for (int g = 0; g < GUT; ++g) {
    const float qs = 127.0f / mxg[g];
    uint2 v; v.x = pack4i8(xa[g].x, xa[g].y, xa[g].z, xa[g].w, qs);
             v.y = pack4i8(xc[g].x, xc[g].y, xc[g].z, xc[g].w, qs);
    reinterpret_cast<uint2*>(xn8)[((size_t)n * GUT + g) * 64 + l] = v;
  }

  float dv = 0.f, xv = 0.f;
#pragma unroll
  for (int g = 0; g < GUT; ++g) {
    const float dxe = (pd[g] - psq[g]) * (1.0f / (GUT - 1));
    float ne2 = (ps - 2.f * pd[g] + psq[g]) * (1.0f / ((GUT - 1) * (GUT - 1)));
    ne2 = fmaxf(ne2, 0.f);
    const float dnm = fmaxf(sqrtf(psq[g]), 1e-8f) * fmaxf(sqrtf(ne2), 1e-8f);
    const float dg = dxe / dnm;
    const float xg = (1.0f / fmaxf(sqrtf(psq[g]), 1e-8f)) * mxg[g] * (1.0f / 127.0f);
    dv = (l == g) ? dg : dv;
    xv = (l == g) ? xg : xv;
  }
  if (l < GUT) { diag[n * GUT + l] = dv; xs[n * GUT + l] = xv; }
  if (l == 0) cs[n] = cscale * ms * (1.0f / 127.0f);
}

// ---------------- Kernel 2: single-i8 MFMA GEMM (round-8 proven loop) + light epilogue ----------------
// Epilogue: per column key_f = (L-MFIX)*log2e feeds BOTH exp2 (se) and the packed argmax key
// (monotone-uint, low 11 bits = 2047-col). Merge = multi-value butterfly: 15+15 shuffles total.
__global__ __launch_bounds__(256, 3) void k2_mfma(
    const unsigned char* __restrict__ xn8, const unsigned char* __restrict__ cn8,
    const float* __restrict__ xs, const float* __restrict__ cs,
    const float* __restrict__ diag, const float* __restrict__ wp,
    const float* __restrict__ bp, float* __restrict__ partial)
{
  __shared__ char ldsb[2 * 16384];            // 32 KB: 2 bufs x {A[8KB], B[8KB]}

  const int tid = threadIdx.x;
  const int l = tid & 63, w = tid >> 6;
  const int rb = blockIdx.x >> 4, cb = blockIdx.x & 15;
  const int rowbase = rb * BM, colbase = cb * BN;

  int4v acc1[4][4];
#pragma unroll
  for (int i = 0; i < 4; ++i)
#pragma unroll
    for (int j = 0; j < 4; ++j)
#pragma unroll
      for (int e = 0; e < 4; ++e) acc1[i][j][e] = 0;

  const int sR = l >> 2;
  const int sC16 = (((l & 3) ^ ((l >> 3) & 3)) << 4);

  const int wr = w >> 1, wc = w & 1;
  const int lr = l & 15, lq = l >> 4;
  int aRel[4], bRel[4];
#pragma unroll
  for (int f = 0; f < 4; ++f) {
    aRel[f] = ((wr * 64 + f * 16 + lr) << 6) + ((lq ^ ((lr >> 1) & 3)) << 4);
    bRel[f] = ((wc * 64 + f * 16 + lr) << 6) + ((lq ^ ((lr >> 1) & 3)) << 4);
  }

#define STAGE(buf, kcn) do {                                                   \
    char* dst_ = ldsb + (buf) * 16384;                                         \
    _Pragma("unroll")                                                          \
    for (int q_ = 0; q_ < 2; ++q_) {                                           \
      const int i_ = w * 2 + q_;                                               \
      const size_t ao_ = (size_t)(rowbase + i_ * 16 + sR) * DIM + (size_t)(kcn) * BK + sC16; \
      const size_t bo_ = (size_t)(colbase + i_ * 16 + sR) * DIM + (size_t)(kcn) * BK + sC16; \
      gload_lds16(xn8 + ao_, dst_ + i_ * 1024);                                \
      gload_lds16(cn8 + bo_, dst_ + 8192 + i_ * 1024);                         \
    }                                                                          \
  } while (0)

  STAGE(0, 0);

  for (int kc = 0; kc < NKC; ++kc) {
    const int cur = kc & 1;
    if (kc < NKC - 1) {
      STAGE(cur ^ 1, kc + 1);
      asm volatile("s_waitcnt vmcnt(4)" ::: "memory");
    } else {
      asm volatile("s_waitcnt vmcnt(0)" ::: "memory");
    }
    __builtin_amdgcn_s_barrier();

    const char* base = ldsb + cur * 16384;
    int4v ah[4], bh4[4];
#pragma unroll
    for (int f = 0; f < 4; ++f) {
      ah[f]  = *reinterpret_cast<const int4v*>(base + aRel[f]);
      bh4[f] = *reinterpret_cast<const int4v*>(base + 8192 + bRel[f]);
    }
    __builtin_amdgcn_s_setprio(1);
#pragma unroll
    for (int mf = 0; mf < 4; ++mf)
#pragma unroll
      for (int nf = 0; nf < 4; ++nf)
        acc1[mf][nf] = __builtin_amdgcn_mfma_i32_16x16x64_i8(ah[mf], bh4[nf], acc1[mf][nf], 0, 0, 0);
    __builtin_amdgcn_s_setprio(0);

    if (kc < NKC - 1) {
      asm volatile("s_waitcnt lgkmcnt(0)" ::: "memory");
      __builtin_amdgcn_s_barrier();
    }
  }
#undef STAGE

  // ---- epilogue ----
  const float wv = wp[0], bvb = bp[0];
  const float MFIX = fabsf(wv) + bvb;                     // upper bound on logits
  const float L2E = 1.4426950408889634f;
  const float wl2e = wv * L2E, bl2e = (bvb - MFIX) * L2E;
  float xc4[4]; int icol[4];
#pragma unroll
  for (int nf = 0; nf < 4; ++nf) {
    const int coll = wc * 64 + nf * 16 + lr;
    xc4[nf] = cs[colbase + coll];
    icol[nf] = 2047 - (colbase + coll);                   // tie-break: lower col wins
  }

  float se16[16]; unsigned kk16[16];
#pragma unroll
  for (int mf = 0; mf < 4; ++mf) {
#pragma unroll
    for (int r = 0; r < 4; ++r) {
      const int p = mf * 4 + r;
      const int row = rowbase + wr * 64 + mf * 16 + lq * 4 + r;
      const float xsr = xs[row];
      const int tcol = row / GUT - colbase;               // target col, block-local
      const float dval = diag[row];
      float se = 0.f; unsigned kk = 0u;
#pragma unroll
      for (int nf = 0; nf < 4; ++nf) {
        const int coll = wc * 64 + nf * 16 + lr;
        float s = (xsr * xc4[nf]) * (float)acc1[mf][nf][r];
        s = (coll == tcol) ? dval : s;
        s = fmaxf(s, 1e-6f);
        const float kf = fmaf(s, wl2e, bl2e);             // (L - MFIX) * log2(e)
        se += exp2f(kf);
        unsigned u = __float_as_uint(kf);
        u ^= (((unsigned)((int)u >> 31)) | 0x80000000u);  // monotone float->uint
        u = (u & 0xFFFFF800u) | (unsigned)icol[nf];
        kk = kk > u ? kk : u;
      }
      se16[p] = se; kk16[p] = kk;
    }
  }

  // ---- multi-value butterfly: 16 pairs over the 16 lanes of each lq-group ----
  float seA[8]; unsigned kkA[8];
  {
    const bool b = lr & 1;
#pragma unroll
    for (int j = 0; j < 8; ++j) {
      const float ss = b ? se16[2*j] : se16[2*j+1];
      const float sk = b ? se16[2*j+1] : se16[2*j];
      seA[j] = sk + __shfl_xor(ss, 1);
      const unsigned us = b ? kk16[2*j] : kk16[2*j+1];
      const unsigned uk = b ? kk16[2*j+1] : kk16[2*j];
      const unsigned ur = (unsigned)__shfl_xor((int)us, 1);
      kkA[j] = uk > ur ? uk : ur;
    }
  }
  float seB[4]; unsigned kkB[4];
  {
    const bool b = (lr >> 1) & 1;
#pragma unroll
    for (int j = 0; j < 4; ++j) {
      const float ss = b ? seA[2*j] : seA[2*j+1];
      const float sk = b ? seA[2*j+1] : seA[2*j];
      seB[j] = sk + __shfl_xor(ss, 2);
      const unsigned us = b ? kkA[2*j] : kkA[2*j+1];
      const unsigned uk = b ? kkA[2*j+1] : kkA[2*j];
      const unsigned ur = (unsigned)__shfl_xor((int)us, 2);
      kkB[j] = uk > ur ? uk : ur;
    }
  }
  float seC[2]; unsigned kkC[2];
  {
    const bool b = (lr >> 2) & 1;
#pragma unroll
    for (int j = 0; j < 2; ++j) {
      const float ss = b ? seB[2*j] : seB[2*j+1];
      const float sk = b ? seB[2*j+1] : seB[2*j];
      seC[j] = sk + __shfl_xor(ss, 4);
      const unsigned us = b ? kkB[2*j] : kkB[2*j+1];
      const unsigned uk = b ? kkB[2*j+1] : kkB[2*j];
      const unsigned ur = (unsigned)__shfl_xor((int)us, 4);
      kkC[j] = uk > ur ? uk : ur;
    }
  }
  float seF; unsigned kkF;
  {
    const bool b = (lr >> 3) & 1;
    const float ss = b ? seC[0] : seC[1];
    const float sk = b ? seC[1] : seC[0];
    seF = sk + __shfl_xor(ss, 8);
    const unsigned us = b ? kkC[0] : kkC[1];
    const unsigned uk = b ? kkC[1] : kkC[0];
    const unsigned ur = (unsigned)__shfl_xor((int)us, 8);
    kkF = uk > ur ? uk : ur;
  }
  // lane lr now owns pair p = lr (bits accumulated low->high), fully reduced over 16 cols.
  {
    const int prow = rowbase + wr * 64 + (lr >> 2) * 16 + lq * 4 + (lr & 3);
    float2 slot; slot.x = seF; slot.y = __uint_as_float(kkF);
    *reinterpret_cast<float2*>(partial + ((size_t)(cb * 2 + wc) * NG + prow) * 2) = slot;
  }
}

// ---------------- Kernel 3: merge 32 half-block partials per row ----------------
__global__ __launch_bounds__(256) void k3_rows(const float* __restrict__ partial,
    const float* __restrict__ diag, const float* __restrict__ wp,
    const float* __restrict__ bp, float* __restrict__ rlp, float* __restrict__ rcr)
{
  const int row = blockIdx.x * 256 + threadIdx.x;
  float se = 0.f; unsigned kk = 0u;
#pragma unroll
  for (int c = 0; c < NHB; ++c) {
    const float2 v = *reinterpret_cast<const float2*>(partial + ((size_t)c * NG + row) * 2);
    se += v.x;
    const unsigned u = __float_as_uint(v.y);
    kk = kk > u ? kk : u;
  }
  const float wv = wp[0], bvb = bp[0];
  const float MFIX = fabsf(wv) + bvb;
  const float st = fmaxf(diag[row], 1e-6f);                // target sim (exact, clamped)
  rlp[row] = fmaf(st, wv, bvb) - MFIX - logf(se);
  const int pred = 2047 - (int)(kk & 0x7FFu);
  rcr[row] = (pred == row / GUT) ? 1.0f : 0.0f;
}

// ---------------- Kernel 4: final scalar reduction ----------------
__global__ __launch_bounds__(256) void k4_reduce(const float* __restrict__ row_logp,
    const float* __restrict__ row_corr, float* __restrict__ out)
{
  const int t = threadIdx.x;
  float sl = 0.f, sc = 0.f;
  for (int i = t; i < NG; i += 256) { sl += row_logp[i]; sc += row_corr[i]; }
  for (int off = 32; off > 0; off >>= 1) { sl += __shfl_down(sl, off); sc += __shfl_down(sc, off); }
  __shared__ float ra[4], rb2[4];
  const int lane = t & 63, wid = t >> 6;
  if (lane == 0) { ra[wid] = sl; rb2[wid] = sc; }
  __syncthreads();
  if (t == 0) {
    const float S = ra[0] + ra[1] + ra[2] + ra[3];
    const float C = rb2[0] + rb2[1] + rb2[2] + rb2[3];
    out[0] = -(S * (1.0f / NG));
    out[1] = C * (100.0f / NG);
  }
}

extern "C" void kernel_launch(void* const* d_in, const int* in_sizes, int n_in,
                              void* d_out, int out_size, void* d_ws, size_t ws_size,
                              hipStream_t stream)
{
  const float* x = (const float*)d_in[0];
  const float* w = (const float*)d_in[1];
  const float* b = (const float*)d_in[2];
  float* out = (float*)d_out;

  char* ws = (char*)d_ws;
  unsigned char* xn8 = (unsigned char*)ws;                            // NG*512 i8
  unsigned char* cn8 = (unsigned char*)(ws + (size_t)NG * DIM);       // NSPK*512 i8
  char* after = ws + (size_t)NG * DIM + (size_t)NSPK * DIM;
  float* xs   = (float*)after;                                        // NG
  float* cs   = xs + NG;                                              // NSPK
  float* diag = cs + NSPK;                                            // NG
  float* part = diag + NG;                                            // NHB*NG*2
  float* rlp  = part + (size_t)NHB * NG * 2;                          // NG
  float* rcr  = rlp + NG;                                             // NG

  hipLaunchKernelGGL(k1_prep, dim3(NSPK), dim3(64), 0, stream,
                     x, xn8, cn8, xs, cs, diag);
  hipLaunchKernelGGL(k2_mfma, dim3(NRB * NCB), dim3(256), 0, stream,
                     xn8, cn8, xs, cs, diag, w, b, part);
  hipLaunchKernelGGL(k3_rows, dim3(NG / 256), dim3(256), 0, stream, part, diag, w, b, rlp, rcr);
  hipLaunchKernelGGL(k4_reduce, dim3(1), dim3(256), 0, stream, rlp, rcr, out);
}

// Round 10
// 78.621 us; speedup vs baseline: 2.2177x; 1.1117x over previous
//
#include <hip/hip_runtime.h>
#include <math.h>

#define NSPK 2048
#define GUT  10
#define DIM  512
#define NG   (NSPK*GUT)

#define BM 128
#define BN 128
#define BK 64
#define NCB (NSPK/BN)   // 16 column blocks
#define NHB (NCB*2)     // 32 column half-blocks (64 cols each)
#define NRB (NG/BM)     // 160 row blocks
#define NKC (DIM/BK)    // 8 K-iterations

typedef __attribute__((ext_vector_type(4))) int int4v;

__device__ inline void gload_lds16(const void* g, void* l) {
  __builtin_amdgcn_global_load_lds(
      (const __attribute__((address_space(1))) void*)g,
      (__attribute__((address_space(3))) void*)l, 16, 0, 0);
}

__device__ __forceinline__ float mergesum(float a, float b, int mask, bool bsel) {
  // pair (a=even-idx, b=odd-idx); keeps b if bsel -> final index bit = lane bit
  const float ss = bsel ? a : b;
  const float sk = bsel ? b : a;
  return sk + __shfl_xor(ss, mask);
}
__device__ inline unsigned pack4i8(float a, float b, float c, float d, float qs) {
  const int q0 = (int)rintf(a * qs) & 255, q1 = (int)rintf(b * qs) & 255;
  const int q2 = (int)rintf(c * qs) & 255, q3 = (int)rintf(d * qs) & 255;
  return (unsigned)q0 | ((unsigned)q1 << 8) | ((unsigned)q2 << 16) | ((unsigned)q3 << 24);
}

// ---------------- Kernel 1: 4 speakers/block (1 wave each); multi-value butterfly ----------------
// Sums reduced with 30 shuffles (vs 126): lane g ends holding psq[g], lane 16+g holds pd[g].
// Quant scale: single speaker-wide max (2 butterflies vs 11).
__global__ __launch_bounds__(256) void k1_prep(const float* __restrict__ x,
    unsigned char* __restrict__ xn8, unsigned char* __restrict__ cn8,
    float* __restrict__ xs, float* __restrict__ cs, float* __restrict__ diag)
{
  const int n = blockIdx.x * 4 + (threadIdx.x >> 6);
  const int l = threadIdx.x & 63;
  const float* xb = x + (size_t)n * GUT * DIM + l * 8;

  float4 xa[GUT], xc[GUT];
#pragma unroll
  for (int g = 0; g < GUT; ++g) {
    xa[g] = *reinterpret_cast<const float4*>(xb + g * DIM);
    xc[g] = *reinterpret_cast<const float4*>(xb + g * DIM + 4);
  }
  float s0=0,s1=0,s2=0,s3=0,s4=0,s5=0,s6=0,s7=0;
#pragma unroll
  for (int g = 0; g < GUT; ++g) {
    s0 += xa[g].x; s1 += xa[g].y; s2 += xa[g].z; s3 += xa[g].w;
    s4 += xc[g].x; s5 += xc[g].y; s6 += xc[g].z; s7 += xc[g].w;
  }
  float P[GUT], D[GUT];
  float mxa = 0.f;
#pragma unroll
  for (int g = 0; g < GUT; ++g) {
    P[g] = xa[g].x*xa[g].x + xa[g].y*xa[g].y + xa[g].z*xa[g].z + xa[g].w*xa[g].w
         + xc[g].x*xc[g].x + xc[g].y*xc[g].y + xc[g].z*xc[g].z + xc[g].w*xc[g].w;
    D[g] = xa[g].x*s0 + xa[g].y*s1 + xa[g].z*s2 + xa[g].w*s3
         + xc[g].x*s4 + xc[g].y*s5 + xc[g].z*s6 + xc[g].w*s7;
    const float m1 = fmaxf(fmaxf(fabsf(xa[g].x), fabsf(xa[g].y)), fmaxf(fabsf(xa[g].z), fabsf(xa[g].w)));
    const float m2 = fmaxf(fmaxf(fabsf(xc[g].x), fabsf(xc[g].y)), fmaxf(fabsf(xc[g].z), fabsf(xc[g].w)));
    mxa = fmaxf(mxa, fmaxf(m1, m2));
  }
  float S = s0*s0+s1*s1+s2*s2+s3*s3+s4*s4+s5*s5+s6*s6+s7*s7;
  float ms = fmaxf(fmaxf(fmaxf(fabsf(s0),fabsf(s1)),fmaxf(fabsf(s2),fabsf(s3))),
                   fmaxf(fmaxf(fabsf(s4),fabsf(s5)),fmaxf(fabsf(s6),fabsf(s7))));

  const bool b0 = l & 1, b1 = l & 2, b2 = l & 4, b3 = l & 8, b4 = l & 16;
  // step 1 (mask 1): 11 shuffles
  float P01 = mergesum(P[0], P[1], 1, b0);
  float P23 = mergesum(P[2], P[3], 1, b0);
  float P45 = mergesum(P[4], P[5], 1, b0);
  float P67 = mergesum(P[6], P[7], 1, b0);
  float P89 = mergesum(P[8], P[9], 1, b0);
  float D01 = mergesum(D[0], D[1], 1, b0);
  float D23 = mergesum(D[2], D[3], 1, b0);
  float D45 = mergesum(D[4], D[5], 1, b0);
  float D67 = mergesum(D[6], D[7], 1, b0);
  float D89 = mergesum(D[8], D[9], 1, b0);
  S += __shfl_xor(S, 1);
  // step 2 (mask 2): 7
  float PA1 = mergesum(P01, P23, 2, b1);
  float PB1 = mergesum(P45, P67, 2, b1);
  float DA1 = mergesum(D01, D23, 2, b1);
  float DB1 = mergesum(D45, D67, 2, b1);
  P89 += __shfl_xor(P89, 2); D89 += __shfl_xor(D89, 2); S += __shfl_xor(S, 2);
  // step 3 (mask 4): 5
  float PA = mergesum(PA1, PB1, 4, b2);
  float DA = mergesum(DA1, DB1, 4, b2);
  P89 += __shfl_xor(P89, 4); D89 += __shfl_xor(D89, 4); S += __shfl_xor(S, 4);
  // step 4 (mask 8): 3
  float PX = mergesum(PA, P89, 8, b3);
  float DX = mergesum(DA, D89, 8, b3);
  S += __shfl_xor(S, 8);
  // step 5 (mask 16): 2
  float V = mergesum(PX, DX, 16, b4);
  S += __shfl_xor(S, 16);
  // step 6 (mask 32): 2
  V += __shfl_xor(V, 32);
  S += __shfl_xor(S, 32);
  // lane l<16 holds P[l&8 ? 8+(l&1) : l&7]; lane 16+l holds D[...]. So lanes 0..9: V=psq[l].

  // speaker-wide maxes (all-lane broadcast)
#pragma unroll
  for (int m = 1; m < 64; m <<= 1) mxa = fmaxf(mxa, __shfl_xor(mxa, m));
#pragma unroll
  for (int m = 1; m < 64; m <<= 1) ms = fmaxf(ms, __shfl_xor(ms, m));

  const float pdv = __shfl(V, l + 16);   // lanes 0..9: pd[l]

  // quantize & store (all lanes)
  const float qs = 127.0f / mxa;
#pragma unroll
  for (int g = 0; g < GUT; ++g) {
    uint2 v; v.x = pack4i8(xa[g].x, xa[g].y, xa[g].z, xa[g].w, qs);
             v.y = pack4i8(xc[g].x, xc[g].y, xc[g].z, xc[g].w, qs);
    reinterpret_cast<uint2*>(xn8)[((size_t)n * GUT + g) * 64 + l] = v;
  }
  const float qsc = 127.0f / ms;
  {
    uint2 cp; cp.x = pack4i8(s0, s1, s2, s3, qsc); cp.y = pack4i8(s4, s5, s6, s7, qsc);
    reinterpret_cast<uint2*>(cn8)[n * 64 + l] = cp;
  }

  if (l < GUT) {
    const float psq = V, pd = pdv;
    const float dxe = (pd - psq) * (1.0f / (GUT - 1));
    float ne2 = (S - 2.f * pd + psq) * (1.0f / ((GUT - 1) * (GUT - 1)));
    ne2 = fmaxf(ne2, 0.f);
    const float rn = fmaxf(sqrtf(psq), 1e-8f);
    diag[n * GUT + l] = dxe / (rn * fmaxf(sqrtf(ne2), 1e-8f));
    xs[n * GUT + l] = mxa / (127.0f * rn);
  }
  if (l == 0) {
    const float cnorm  = sqrtf(S) * (1.0f / GUT);
    const float cscale = (1.0f / GUT) / fmaxf(cnorm, 1e-8f);
    cs[n] = cscale * ms * (1.0f / 127.0f);
  }
}

// ---------------- Kernel 2: single-i8 MFMA GEMM (proven loop) + (se,maxkf) epilogue ----------------
__global__ __launch_bounds__(256, 4) void k2_mfma(
    const unsigned char* __restrict__ xn8, const unsigned char* __restrict__ cn8,
    const float* __restrict__ xs, const float* __restrict__ cs,
    const float* __restrict__ diag, const float* __restrict__ wp,
    const float* __restrict__ bp, float* __restrict__ partial)
{
  __shared__ char ldsb[2 * 16384];            // 32 KB: 2 bufs x {A[8KB], B[8KB]}

  const int tid = threadIdx.x;
  const int l = tid & 63, w = tid >> 6;
  const int rb = blockIdx.x >> 4, cb = blockIdx.x & 15;
  const int rowbase = rb * BM, colbase = cb * BN;

  int4v acc1[4][4];
#pragma unroll
  for (int i = 0; i < 4; ++i)
#pragma unroll
    for (int j = 0; j < 4; ++j)
#pragma unroll
      for (int e = 0; e < 4; ++e) acc1[i][j][e] = 0;

  const int sR = l >> 2;
  const int sC16 = (((l & 3) ^ ((l >> 3) & 3)) << 4);

  const int wr = w >> 1, wc = w & 1;
  const int lr = l & 15, lq = l >> 4;
  int aRel[4], bRel[4];
#pragma unroll
  for (int f = 0; f < 4; ++f) {
    aRel[f] = ((wr * 64 + f * 16 + lr) << 6) + ((lq ^ ((lr >> 1) & 3)) << 4);
    bRel[f] = ((wc * 64 + f * 16 + lr) << 6) + ((lq ^ ((lr >> 1) & 3)) << 4);
  }

#define STAGE(buf, kcn) do {                                                   \
    char* dst_ = ldsb + (buf) * 16384;                                         \
    _Pragma("unroll")                                                          \
    for (int q_ = 0; q_ < 2; ++q_) {                                           \
      const int i_ = w * 2 + q_;                                               \
      const size_t ao_ = (size_t)(rowbase + i_ * 16 + sR) * DIM + (size_t)(kcn) * BK + sC16; \
      const size_t bo_ = (size_t)(colbase + i_ * 16 + sR) * DIM + (size_t)(kcn) * BK + sC16; \
      gload_lds16(xn8 + ao_, dst_ + i_ * 1024);                                \
      gload_lds16(cn8 + bo_, dst_ + 8192 + i_ * 1024);                         \
    }                                                                          \
  } while (0)

  STAGE(0, 0);

  for (int kc = 0; kc < NKC; ++kc) {
    const int cur = kc & 1;
    if (kc < NKC - 1) {
      STAGE(cur ^ 1, kc + 1);
      asm volatile("s_waitcnt vmcnt(4)" ::: "memory");
    } else {
      asm volatile("s_waitcnt vmcnt(0)" ::: "memory");
    }
    __builtin_amdgcn_s_barrier();

    const char* base = ldsb + cur * 16384;
    int4v ah[4], bh4[4];
#pragma unroll
    for (int f = 0; f < 4; ++f) {
      ah[f]  = *reinterpret_cast<const int4v*>(base + aRel[f]);
      bh4[f] = *reinterpret_cast<const int4v*>(base + 8192 + bRel[f]);
    }
    __builtin_amdgcn_s_setprio(1);
#pragma unroll
    for (int mf = 0; mf < 4; ++mf)
#pragma unroll
      for (int nf = 0; nf < 4; ++nf)
        acc1[mf][nf] = __builtin_amdgcn_mfma_i32_16x16x64_i8(ah[mf], bh4[nf], acc1[mf][nf], 0, 0, 0);
    __builtin_amdgcn_s_setprio(0);

    if (kc < NKC - 1) {
      asm volatile("s_waitcnt lgkmcnt(0)" ::: "memory");
      __builtin_amdgcn_s_barrier();
    }
  }
#undef STAGE

  // ---- epilogue: per-col kf = (L-MFIX)*log2e; carry (se = sum 2^kf, mx = max kf) ----
  const float wv = wp[0], bvb = bp[0];
  const float MFIX = fabsf(wv) + bvb;
  const float L2E = 1.4426950408889634f;
  const float wl2e = wv * L2E, bl2e = (bvb - MFIX) * L2E;
  float xc4[4];
#pragma unroll
  for (int nf = 0; nf < 4; ++nf)
    xc4[nf] = cs[colbase + wc * 64 + nf * 16 + lr];

  float se16[16], mx16[16];
#pragma unroll
  for (int mf = 0; mf < 4; ++mf) {
#pragma unroll
    for (int r = 0; r < 4; ++r) {
      const int p = mf * 4 + r;
      const int row = rowbase + wr * 64 + mf * 16 + lq * 4 + r;
      const float xsr = xs[row];
      const int tcol = row / GUT - colbase;
      const float dval = diag[row];
      float se = 0.f, mxk = -__builtin_inff();
#pragma unroll
      for (int nf = 0; nf < 4; ++nf) {
        const int coll = wc * 64 + nf * 16 + lr;
        float s = (xsr * xc4[nf]) * (float)acc1[mf][nf][r];
        s = (coll == tcol) ? dval : s;
        s = fmaxf(s, 1e-6f);
        const float kf = fmaf(s, wl2e, bl2e);
        se += exp2f(kf);
        mxk = fmaxf(mxk, kf);
      }
      se16[p] = se; mx16[p] = mxk;
    }
  }

  // ---- multi-value butterfly over the 16 lanes of each lq-group ----
  float seA[8], mxA[8];
  {
    const bool b = lr & 1;
#pragma unroll
    for (int j = 0; j < 8; ++j) {
      seA[j] = (b ? se16[2*j+1] : se16[2*j]) + __shfl_xor(b ? se16[2*j] : se16[2*j+1], 1);
      mxA[j] = fmaxf(b ? mx16[2*j+1] : mx16[2*j], __shfl_xor(b ? mx16[2*j] : mx16[2*j+1], 1));
    }
  }
  float seB[4], mxB[4];
  {
    const bool b = (lr >> 1) & 1;
#pragma unroll
    for (int j = 0; j < 4; ++j) {
      seB[j] = (b ? seA[2*j+1] : seA[2*j]) + __shfl_xor(b ? seA[2*j] : seA[2*j+1], 2);
      mxB[j] = fmaxf(b ? mxA[2*j+1] : mxA[2*j], __shfl_xor(b ? mxA[2*j] : mxA[2*j+1], 2));
    }
  }
  float seC[2], mxC[2];
  {
    const bool b = (lr >> 2) & 1;
#pragma unroll
    for (int j = 0; j < 2; ++j) {
      seC[j] = (b ? seB[2*j+1] : seB[2*j]) + __shfl_xor(b ? seB[2*j] : seB[2*j+1], 4);
      mxC[j] = fmaxf(b ? mxB[2*j+1] : mxB[2*j], __shfl_xor(b ? mxB[2*j] : mxB[2*j+1], 4));
    }
  }
  float seF, mxF;
  {
    const bool b = (lr >> 3) & 1;
    seF = (b ? seC[1] : seC[0]) + __shfl_xor(b ? seC[0] : seC[1], 8);
    mxF = fmaxf(b ? mxC[1] : mxC[0], __shfl_xor(b ? mxC[0] : mxC[1], 8));
  }
  {
    const int prow = rowbase + wr * 64 + (lr >> 2) * 16 + lq * 4 + (lr & 3);
    float2 slot; slot.x = seF; slot.y = mxF;
    *reinterpret_cast<float2*>(partial + ((size_t)(cb * 2 + wc) * NG + prow) * 2) = slot;
  }
}

// ---------------- Kernel 3: merge 32 half-block partials per row ----------------
__global__ __launch_bounds__(256) void k3_rows(const float* __restrict__ partial,
    const float* __restrict__ diag, const float* __restrict__ wp,
    const float* __restrict__ bp, float* __restrict__ rlp, float* __restrict__ rcr)
{
  const int row = blockIdx.x * 256 + threadIdx.x;
  float se = 0.f, mx = -__builtin_inff();
#pragma unroll
  for (int c = 0; c < NHB; ++c) {
    const float2 v = *reinterpret_cast<const float2*>(partial + ((size_t)c * NG + row) * 2);
    se += v.x;
    mx = fmaxf(mx, v.y);
  }
  const float wv = wp[0], bvb = bp[0];
  const float MFIX = fabsf(wv) + bvb;
  const float L2E = 1.4426950408889634f;
  const float wl2e = wv * L2E, bl2e = (bvb - MFIX) * L2E;
  // target kf: identical op sequence to k2's substitution path -> bit-exact match
  const float tg = fmaf(fmaxf(diag[row], 1e-6f), wl2e, bl2e);
  rlp[row] = tg * 0.6931471805599453f - logf(se);
  rcr[row] = (tg >= mx) ? 1.0f : 0.0f;
}

// ---------------- Kernel 4: final scalar reduction ----------------
__global__ __launch_bounds__(256) void k4_reduce(const float* __restrict__ row_logp,
    const float* __restrict__ row_corr, float* __restrict__ out)
{
  const int t = threadIdx.x;
  float sl = 0.f, sc = 0.f;
  for (int i = t; i < NG; i += 256) { sl += row_logp[i]; sc += row_corr[i]; }
  for (int off = 32; off > 0; off >>= 1) { sl += __shfl_down(sl, off); sc += __shfl_down(sc, off); }
  __shared__ float ra[4], rb2[4];
  const int lane = t & 63, wid = t >> 6;
  if (lane == 0) { ra[wid] = sl; rb2[wid] = sc; }
  __syncthreads();
  if (t == 0) {
    const float S = ra[0] + ra[1] + ra[2] + ra[3];
    const float C = rb2[0] + rb2[1] + rb2[2] + rb2[3];
    out[0] = -(S * (1.0f / NG));
    out[1] = C * (100.0f / NG);
  }
}

extern "C" void kernel_launch(void* const* d_in, const int* in_sizes, int n_in,
                              void* d_out, int out_size, void* d_ws, size_t ws_size,
                              hipStream_t stream)
{
  const float* x = (const float*)d_in[0];
  const float* w = (const float*)d_in[1];
  const float* b = (const float*)d_in[2];
  float* out = (float*)d_out;

  char* ws = (char*)d_ws;
  unsigned char* xn8 = (unsigned char*)ws;                            // NG*512 i8
  unsigned char* cn8 = (unsigned char*)(ws + (size_t)NG * DIM);       // NSPK*512 i8
  char* after = ws + (size_t)NG * DIM + (size_t)NSPK * DIM;
  float* xs   = (float*)after;                                        // NG
  float* cs   = xs + NG;                                              // NSPK
  float* diag = cs + NSPK;                                            // NG
  float* part = diag + NG;                                            // NHB*NG*2
  float* rlp  = part + (size_t)NHB * NG * 2;                          // NG
  float* rcr  = rlp + NG;                                             // NG

  hipLaunchKernelGGL(k1_prep, dim3(NSPK / 4), dim3(256), 0, stream,
                     x, xn8, cn8, xs, cs, diag);
  hipLaunchKernelGGL(k2_mfma, dim3(NRB * NCB), dim3(256), 0, stream,
                     xn8, cn8, xs, cs, diag, w, b, part);
  hipLaunchKernelGGL(k3_rows, dim3(NG / 256), dim3(256), 0, stream, part, diag, w, b, rlp, rcr);
  hipLaunchKernelGGL(k4_reduce, dim3(1), dim3(256), 0, stream, rlp, rcr, out);
}